// Round 1
// baseline (297.385 us; speedup 1.0000x reference)
//
#include <hip/hip_runtime.h>
#include <math.h>

// Problem geometry (fixed by the reference): B=32, C=16, H=W=256.
#define HW 65536
#define HW4 16384          // float4 groups per channel-plane
#define CTOT 16
#define BATCH 32
#define NPIX (BATCH * HW)  // 2,097,152 pixels per channel
#define NGRP (NPIX / 4)    // 524,288 float4 groups

// Accumulator slots in workspace (double[22]):
//  0.. 2 : ch15 line_seg  (sumPosLoss, sumNegLoss, cntPos)
//  3.. 5 : ch14 junc_seg
//  6.. 8 : ch0  sol_center
//  9..11 : ch7  tp_center
// 12..13 : sol disp (sumMinLoss, cntPos)
// 14..15 : tp  disp
// 16..18 : sol len/angle (sumLen, sumAngle, cntPos)
// 19..21 : tp  len/angle
#define NACC 22

__device__ __forceinline__ float smooth_l1(float p, float g) {
    float d = fabsf(p - g);
    return (d < 1.0f) ? 0.5f * d * d : d - 0.5f;
}
__device__ __forceinline__ float bce_logits(float x, float t) {
    return fmaxf(x, 0.0f) - x * t + log1pf(expf(-fabsf(x)));
}
__device__ __forceinline__ float sigmoidf_(float x) {
    return 1.0f / (1.0f + expf(-x));
}
__device__ __forceinline__ float get4(const float4& v, int j) {
    return j == 0 ? v.x : (j == 1 ? v.y : (j == 2 ? v.z : v.w));
}

__global__ __launch_bounds__(256) void loss_kernel(const float* __restrict__ preds,
                                                   const float* __restrict__ gts,
                                                   double* __restrict__ ws) {
    float acc[NACC];
#pragma unroll
    for (int i = 0; i < NACC; ++i) acc[i] = 0.0f;

    const int gtid = blockIdx.x * blockDim.x + threadIdx.x;
    const int stride = gridDim.x * blockDim.x;

    for (int g = gtid; g < NGRP; g += stride) {
        const int b   = g >> 14;           // HW4 = 2^14
        const int hw4 = g & (HW4 - 1);
        const float4* pb = (const float4*)preds + (size_t)b * (CTOT * HW4) + hw4;
        const float4* gb = (const float4*)gts   + (size_t)b * (CTOT * HW4) + hw4;

        // ---- 4 weighted-BCE channels: (channel, acc base) ----
        {
            const int ch[4]   = {15, 14, 0, 7};
            const int base[4] = {0, 3, 6, 9};
#pragma unroll
            for (int k = 0; k < 4; ++k) {
                float4 p = pb[(size_t)ch[k] * HW4];
                float4 t = gb[(size_t)ch[k] * HW4];
#pragma unroll
                for (int j = 0; j < 4; ++j) {
                    float x  = get4(p, j);
                    float tv = get4(t, j);
                    float loss = bce_logits(x, tv);
                    float pos  = (tv != 0.0f) ? 1.0f : 0.0f;
                    acc[base[k] + 0] += loss * pos;
                    acc[base[k] + 1] += loss * (1.0f - pos);
                    acc[base[k] + 2] += pos;
                }
            }
        }

        // ---- displacement groups: sol = ch1..4 (acc 12,13), tp = ch8..11 (acc 14,15) ----
        {
            const int c0[2]   = {1, 8};
            const int base[2] = {12, 14};
#pragma unroll
            for (int k = 0; k < 2; ++k) {
                float4 p0 = pb[(size_t)(c0[k] + 0) * HW4];
                float4 p1 = pb[(size_t)(c0[k] + 1) * HW4];
                float4 p2 = pb[(size_t)(c0[k] + 2) * HW4];
                float4 p3 = pb[(size_t)(c0[k] + 3) * HW4];
                float4 g0 = gb[(size_t)(c0[k] + 0) * HW4];
                float4 g1 = gb[(size_t)(c0[k] + 1) * HW4];
                float4 g2 = gb[(size_t)(c0[k] + 2) * HW4];
                float4 g3 = gb[(size_t)(c0[k] + 3) * HW4];
#pragma unroll
                for (int j = 0; j < 4; ++j) {
                    float a0 = get4(p0, j), a1 = get4(p1, j), a2 = get4(p2, j), a3 = get4(p3, j);
                    float b0 = get4(g0, j), b1 = get4(g1, j), b2 = get4(g2, j), b3 = get4(g3, j);
                    float posv = fabsf(b0) + fabsf(b1) + fabsf(b2) + fabsf(b3);
                    float m = (posv != 0.0f) ? 1.0f : 0.0f;
                    // masked inputs == multiplying min(loss1,loss2) by m (sl1(0,0)=0)
                    float l1 = smooth_l1(a0, b0) + smooth_l1(a1, b1) +
                               smooth_l1(a2, b2) + smooth_l1(a3, b3);
                    // swap = concat(pred[2:], pred[:2]) -> [p2,p3,p0,p1] vs gt [g0,g1,g2,g3]
                    float l2 = smooth_l1(a2, b0) + smooth_l1(a3, b1) +
                               smooth_l1(a0, b2) + smooth_l1(a1, b3);
                    acc[base[k] + 0] += fminf(l1, l2) * m;
                    acc[base[k] + 1] += m;
                }
            }
        }

        // ---- len/angle: sol = ch5/6 (acc 16..18), tp = ch12/13 (acc 19..21) ----
        {
            const int cl[2]   = {5, 12};
            const int base[2] = {16, 19};
#pragma unroll
            for (int k = 0; k < 2; ++k) {
                float4 pl = pb[(size_t)(cl[k] + 0) * HW4];
                float4 pa = pb[(size_t)(cl[k] + 1) * HW4];
                float4 gl = gb[(size_t)(cl[k] + 0) * HW4];
                float4 ga = gb[(size_t)(cl[k] + 1) * HW4];
#pragma unroll
                for (int j = 0; j < 4; ++j) {
                    float glv = get4(gl, j);
                    float m = (glv != 0.0f) ? 1.0f : 0.0f;
                    acc[base[k] + 0] += smooth_l1(sigmoidf_(get4(pl, j)), glv) * m;
                    acc[base[k] + 1] += smooth_l1(sigmoidf_(get4(pa, j)), get4(ga, j)) * m;
                    acc[base[k] + 2] += m;
                }
            }
        }
    }

    // ---- wave (64-lane) butterfly reduce each accumulator ----
#pragma unroll
    for (int i = 0; i < NACC; ++i) {
        float v = acc[i];
#pragma unroll
        for (int off = 32; off > 0; off >>= 1) v += __shfl_down(v, off, 64);
        acc[i] = v;
    }

    __shared__ float red[4][NACC];
    const int lane = threadIdx.x & 63;
    const int wid  = threadIdx.x >> 6;
    if (lane == 0) {
#pragma unroll
        for (int i = 0; i < NACC; ++i) red[wid][i] = acc[i];
    }
    __syncthreads();
    if (threadIdx.x < NACC) {
        float s = red[0][threadIdx.x] + red[1][threadIdx.x] +
                  red[2][threadIdx.x] + red[3][threadIdx.x];
        atomicAdd(&ws[threadIdx.x], (double)s);
    }
}

__global__ void finalize_kernel(const double* __restrict__ ws, float* __restrict__ out) {
    if (threadIdx.x == 0 && blockIdx.x == 0) {
        const double N = (double)NPIX;
        // weighted BCE: loss_pos * pos_w + loss_neg * neg_w (pos_w = 1 everywhere)
        double line_seg   = ws[0] / ws[2]  +  1.0 * (ws[1]  / (N - ws[2]));
        double junc_seg   = ws[3] / ws[5]  + 30.0 * (ws[4]  / (N - ws[5]));
        double sol_center = ws[6] / ws[8]  + 30.0 * (ws[7]  / (N - ws[8]));
        double tp_center  = ws[9] / ws[11] + 30.0 * (ws[10] / (N - ws[11]));
        double sol_disp   = ws[12] / ws[13];
        double tp_disp    = ws[14] / ws[15];
        double sol_len    = ws[16] / ws[18];
        double sol_angle  = ws[17] / ws[18];
        double tp_len     = ws[19] / ws[21];
        double tp_angle   = ws[20] / ws[21];
        double total = 10.0 * tp_center + tp_disp + tp_len + tp_angle +
                       sol_center + sol_disp + sol_len + sol_angle +
                       line_seg + junc_seg;
        out[0] = (float)total;
    }
}

extern "C" void kernel_launch(void* const* d_in, const int* in_sizes, int n_in,
                              void* d_out, int out_size, void* d_ws, size_t ws_size,
                              hipStream_t stream) {
    const float* preds = (const float*)d_in[0];
    const float* gts   = (const float*)d_in[1];
    // d_in[2], d_in[3] (line lists) are unused by the reference computation.
    double* ws = (double*)d_ws;

    // d_ws is re-poisoned to 0xAA before every launch — zero the accumulators.
    hipMemsetAsync(d_ws, 0, NACC * sizeof(double), stream);

    // 1024 blocks x 256 threads = 262,144 threads, 2 float4 groups each.
    loss_kernel<<<1024, 256, 0, stream>>>(preds, gts, ws);
    finalize_kernel<<<1, 64, 0, stream>>>(ws, (float*)d_out);
}

// Round 2
// 295.647 us; speedup vs baseline: 1.0059x; 1.0059x over previous
//
#include <hip/hip_runtime.h>
#include <math.h>

// Problem geometry (fixed by the reference): B=32, C=16, H=W=256.
#define HW 65536
#define HW4 16384          // float4 groups per channel-plane
#define CTOT 16
#define BATCH 32
#define NPIX (BATCH * HW)  // 2,097,152 pixels per channel
#define NGRP (NPIX / 4)    // 524,288 float4 groups per channel

// Accumulator slots in workspace (double[22]):
//  0.. 2 : ch15 line_seg  (sumPosLoss, sumNegLoss, cntPos)
//  3.. 5 : ch14 junc_seg
//  6.. 8 : ch0  sol_center
//  9..11 : ch7  tp_center
// 12..13 : sol disp (sumMinLoss, cntPos)
// 14..15 : tp  disp
// 16..18 : sol len/angle (sumLen, sumAngle, cntPos)
// 19..21 : tp  len/angle
#define NACC 22

// Task layout: 2048 blocks total, share proportional to planes touched so
// every thread does exactly 32 float4 loads.
//   blocks    0..511  : 4 BCE tasks (ch 15,14,0,7), 128 blocks each, 2 planes
//   blocks  512..1535 : 2 disp tasks (c0=1, c0=8), 512 blocks each, 8 planes
//   blocks 1536..2047 : 2 len/angle tasks (cl=5, cl=12), 256 blocks each, 4 planes
#define GRID_BLOCKS 2048

__device__ __forceinline__ float smooth_l1(float p, float g) {
    float d = fabsf(p - g);
    return (d < 1.0f) ? 0.5f * d * d : d - 0.5f;
}
__device__ __forceinline__ float bce_logits(float x, float t) {
    return fmaxf(x, 0.0f) - x * t + log1pf(expf(-fabsf(x)));
}
__device__ __forceinline__ float sigmoidf_(float x) {
    return 1.0f / (1.0f + expf(-x));
}
__device__ __forceinline__ float get4(const float4& v, int j) {
    return j == 0 ? v.x : (j == 1 ? v.y : (j == 2 ? v.z : v.w));
}

__global__ __launch_bounds__(256) void loss_kernel(const float* __restrict__ preds,
                                                   const float* __restrict__ gts,
                                                   double* __restrict__ ws) {
    const float4* pf = (const float4*)preds;
    const float4* gf = (const float4*)gts;
    const int blk = blockIdx.x;

    float acc0 = 0.0f, acc1 = 0.0f, acc2 = 0.0f;
    int base, nacc;

    if (blk < 512) {
        // ---------------- BCE task ----------------
        const int task = blk >> 7;                    // 0..3
        const int chs[4]   = {15, 14, 0, 7};
        const int bases[4] = {0, 3, 6, 9};
        const int ch = chs[task];
        base = bases[task];
        nacc = 3;
        const int lthread = ((blk & 127) << 8) + threadIdx.x;   // 0..32767
        const int tstride = 128 * 256;                          // 32768 -> 16 iters
#pragma unroll 2
        for (int g = lthread; g < NGRP; g += tstride) {
            const int b = g >> 14, hw4 = g & (HW4 - 1);
            const size_t off = ((size_t)b * CTOT + ch) * HW4 + hw4;
            float4 p = pf[off];
            float4 t = gf[off];
#pragma unroll
            for (int j = 0; j < 4; ++j) {
                float x  = get4(p, j);
                float tv = get4(t, j);
                float loss = bce_logits(x, tv);
                float pos  = (tv != 0.0f) ? 1.0f : 0.0f;
                acc0 += loss * pos;
                acc1 += loss * (1.0f - pos);
                acc2 += pos;
            }
        }
    } else if (blk < 1536) {
        // ---------------- displacement task ----------------
        const int task = (blk - 512) >> 9;            // 0..1
        const int c0 = task == 0 ? 1 : 8;
        base = task == 0 ? 12 : 14;
        nacc = 2;
        const int lblk = (blk - 512) & 511;
        const int lthread = (lblk << 8) + threadIdx.x;          // 0..131071
        const int tstride = 512 * 256;                          // 131072 -> 4 iters
        for (int g = lthread; g < NGRP; g += tstride) {
            const int b = g >> 14, hw4 = g & (HW4 - 1);
            const size_t off = ((size_t)b * CTOT + c0) * HW4 + hw4;
            float4 p0 = pf[off + 0 * HW4];
            float4 p1 = pf[off + 1 * HW4];
            float4 p2 = pf[off + 2 * HW4];
            float4 p3 = pf[off + 3 * HW4];
            float4 g0 = gf[off + 0 * HW4];
            float4 g1 = gf[off + 1 * HW4];
            float4 g2 = gf[off + 2 * HW4];
            float4 g3 = gf[off + 3 * HW4];
#pragma unroll
            for (int j = 0; j < 4; ++j) {
                float a0 = get4(p0, j), a1 = get4(p1, j), a2 = get4(p2, j), a3 = get4(p3, j);
                float b0 = get4(g0, j), b1 = get4(g1, j), b2 = get4(g2, j), b3 = get4(g3, j);
                float posv = fabsf(b0) + fabsf(b1) + fabsf(b2) + fabsf(b3);
                float m = (posv != 0.0f) ? 1.0f : 0.0f;
                float l1 = smooth_l1(a0, b0) + smooth_l1(a1, b1) +
                           smooth_l1(a2, b2) + smooth_l1(a3, b3);
                // swap = concat(pred[2:], pred[:2]) -> [p2,p3,p0,p1] vs gt
                float l2 = smooth_l1(a2, b0) + smooth_l1(a3, b1) +
                           smooth_l1(a0, b2) + smooth_l1(a1, b3);
                acc0 += fminf(l1, l2) * m;
                acc1 += m;
            }
        }
    } else {
        // ---------------- len/angle task ----------------
        const int task = (blk - 1536) >> 8;           // 0..1
        const int cl = task == 0 ? 5 : 12;
        base = task == 0 ? 16 : 19;
        nacc = 3;
        const int lblk = (blk - 1536) & 255;
        const int lthread = (lblk << 8) + threadIdx.x;          // 0..65535
        const int tstride = 256 * 256;                          // 65536 -> 8 iters
#pragma unroll 2
        for (int g = lthread; g < NGRP; g += tstride) {
            const int b = g >> 14, hw4 = g & (HW4 - 1);
            const size_t off = ((size_t)b * CTOT + cl) * HW4 + hw4;
            float4 pl = pf[off + 0 * HW4];
            float4 pa = pf[off + 1 * HW4];
            float4 gl = gf[off + 0 * HW4];
            float4 ga = gf[off + 1 * HW4];
#pragma unroll
            for (int j = 0; j < 4; ++j) {
                float glv = get4(gl, j);
                float m = (glv != 0.0f) ? 1.0f : 0.0f;
                acc0 += smooth_l1(sigmoidf_(get4(pl, j)), glv) * m;
                acc1 += smooth_l1(sigmoidf_(get4(pa, j)), get4(ga, j)) * m;
                acc2 += m;
            }
        }
    }

    // ---- wave (64-lane) butterfly reduce the (up to) 3 accumulators ----
#pragma unroll
    for (int off = 32; off > 0; off >>= 1) {
        acc0 += __shfl_down(acc0, off, 64);
        acc1 += __shfl_down(acc1, off, 64);
        acc2 += __shfl_down(acc2, off, 64);
    }

    __shared__ float red[4][3];
    const int lane = threadIdx.x & 63;
    const int wid  = threadIdx.x >> 6;
    if (lane == 0) { red[wid][0] = acc0; red[wid][1] = acc1; red[wid][2] = acc2; }
    __syncthreads();
    if (threadIdx.x == 0) {
        float s0 = red[0][0] + red[1][0] + red[2][0] + red[3][0];
        float s1 = red[0][1] + red[1][1] + red[2][1] + red[3][1];
        float s2 = red[0][2] + red[1][2] + red[2][2] + red[3][2];
        atomicAdd(&ws[base + 0], (double)s0);
        atomicAdd(&ws[base + 1], (double)s1);
        if (nacc == 3) atomicAdd(&ws[base + 2], (double)s2);
    }
}

__global__ void finalize_kernel(const double* __restrict__ ws, float* __restrict__ out) {
    if (threadIdx.x == 0 && blockIdx.x == 0) {
        const double N = (double)NPIX;
        double line_seg   = ws[0] / ws[2]  +  1.0 * (ws[1]  / (N - ws[2]));
        double junc_seg   = ws[3] / ws[5]  + 30.0 * (ws[4]  / (N - ws[5]));
        double sol_center = ws[6] / ws[8]  + 30.0 * (ws[7]  / (N - ws[8]));
        double tp_center  = ws[9] / ws[11] + 30.0 * (ws[10] / (N - ws[11]));
        double sol_disp   = ws[12] / ws[13];
        double tp_disp    = ws[14] / ws[15];
        double sol_len    = ws[16] / ws[18];
        double sol_angle  = ws[17] / ws[18];
        double tp_len     = ws[19] / ws[21];
        double tp_angle   = ws[20] / ws[21];
        double total = 10.0 * tp_center + tp_disp + tp_len + tp_angle +
                       sol_center + sol_disp + sol_len + sol_angle +
                       line_seg + junc_seg;
        out[0] = (float)total;
    }
}

extern "C" void kernel_launch(void* const* d_in, const int* in_sizes, int n_in,
                              void* d_out, int out_size, void* d_ws, size_t ws_size,
                              hipStream_t stream) {
    const float* preds = (const float*)d_in[0];
    const float* gts   = (const float*)d_in[1];
    double* ws = (double*)d_ws;

    // d_ws is re-poisoned to 0xAA before every launch — zero the accumulators.
    hipMemsetAsync(d_ws, 0, NACC * sizeof(double), stream);

    loss_kernel<<<GRID_BLOCKS, 256, 0, stream>>>(preds, gts, ws);
    finalize_kernel<<<1, 64, 0, stream>>>(ws, (float*)d_out);
}

// Round 3
// 292.918 us; speedup vs baseline: 1.0152x; 1.0093x over previous
//
#include <hip/hip_runtime.h>
#include <math.h>

// Problem geometry (fixed by the reference): B=32, C=16, H=W=256.
#define HW 65536
#define HW4 16384          // float4 groups per channel-plane
#define CTOT 16
#define BATCH 32
#define NPIX (BATCH * HW)  // 2,097,152 pixels per channel
#define NGRP (NPIX / 4)    // 524,288 float4 groups per channel

// Accumulator slots in workspace (double[22]):
//  0.. 2 : ch15 line_seg  (sumPosLoss, sumNegLoss, cntPos)
//  3.. 5 : ch14 junc_seg
//  6.. 8 : ch0  sol_center
//  9..11 : ch7  tp_center
// 12..13 : sol disp (sumMinLoss, cntPos)
// 14..15 : tp  disp
// 16..18 : sol len/angle (sumLen, sumAngle, cntPos)
// 19..21 : tp  len/angle
#define NACC 22

#define GRID_BLOCKS 2048   // 2048*256 threads = 524,288 = NGRP -> 1 group/thread

__device__ __forceinline__ float smooth_l1(float p, float g) {
    float d = fabsf(p - g);
    return (d < 1.0f) ? 0.5f * d * d : d - 0.5f;
}
// Fast BCE-with-logits. a=|x| >= 0, so 1+exp(-a) in (1,2]: plain __logf is
// numerically safe (worst-case abs err < 6e-8; pass threshold is 6.12).
__device__ __forceinline__ float bce_logits(float x, float t) {
    float e = __expf(-fabsf(x));           // v_exp_f32 path
    return fmaxf(x, 0.0f) - x * t + __logf(1.0f + e);  // v_log_f32 path
}
__device__ __forceinline__ float sigmoid_fast(float x) {
    return __builtin_amdgcn_rcpf(1.0f + __expf(-x));   // v_rcp_f32
}
__device__ __forceinline__ float get4(const float4& v, int j) {
    return j == 0 ? v.x : (j == 1 ? v.y : (j == 2 ? v.z : v.w));
}

__global__ __launch_bounds__(256) void loss_kernel(const float* __restrict__ preds,
                                                   const float* __restrict__ gts,
                                                   double* __restrict__ ws) {
    float acc[NACC];
#pragma unroll
    for (int i = 0; i < NACC; ++i) acc[i] = 0.0f;

    const int gtid = blockIdx.x * blockDim.x + threadIdx.x;
    const int stride = gridDim.x * blockDim.x;

    for (int g = gtid; g < NGRP; g += stride) {
        const int b   = g >> 14;           // HW4 = 2^14
        const int hw4 = g & (HW4 - 1);
        const float4* pb = (const float4*)preds + (size_t)b * (CTOT * HW4) + hw4;
        const float4* gb = (const float4*)gts   + (size_t)b * (CTOT * HW4) + hw4;

        // ---- 4 weighted-BCE channels ----
        {
            const int ch[4]   = {15, 14, 0, 7};
            const int base[4] = {0, 3, 6, 9};
#pragma unroll
            for (int k = 0; k < 4; ++k) {
                float4 p = pb[(size_t)ch[k] * HW4];
                float4 t = gb[(size_t)ch[k] * HW4];
#pragma unroll
                for (int j = 0; j < 4; ++j) {
                    float x  = get4(p, j);
                    float tv = get4(t, j);
                    float loss = bce_logits(x, tv);
                    float pos  = (tv != 0.0f) ? 1.0f : 0.0f;
                    acc[base[k] + 0] += loss * pos;
                    acc[base[k] + 1] += loss * (1.0f - pos);
                    acc[base[k] + 2] += pos;
                }
            }
        }

        // ---- displacement groups: sol=ch1..4 (acc 12,13), tp=ch8..11 (14,15) ----
        {
            const int c0[2]   = {1, 8};
            const int base[2] = {12, 14};
#pragma unroll
            for (int k = 0; k < 2; ++k) {
                float4 p0 = pb[(size_t)(c0[k] + 0) * HW4];
                float4 p1 = pb[(size_t)(c0[k] + 1) * HW4];
                float4 p2 = pb[(size_t)(c0[k] + 2) * HW4];
                float4 p3 = pb[(size_t)(c0[k] + 3) * HW4];
                float4 g0 = gb[(size_t)(c0[k] + 0) * HW4];
                float4 g1 = gb[(size_t)(c0[k] + 1) * HW4];
                float4 g2 = gb[(size_t)(c0[k] + 2) * HW4];
                float4 g3 = gb[(size_t)(c0[k] + 3) * HW4];
#pragma unroll
                for (int j = 0; j < 4; ++j) {
                    float a0 = get4(p0, j), a1 = get4(p1, j), a2 = get4(p2, j), a3 = get4(p3, j);
                    float b0 = get4(g0, j), b1 = get4(g1, j), b2 = get4(g2, j), b3 = get4(g3, j);
                    float posv = fabsf(b0) + fabsf(b1) + fabsf(b2) + fabsf(b3);
                    float m = (posv != 0.0f) ? 1.0f : 0.0f;
                    float l1 = smooth_l1(a0, b0) + smooth_l1(a1, b1) +
                               smooth_l1(a2, b2) + smooth_l1(a3, b3);
                    // swap = concat(pred[2:], pred[:2]) -> [p2,p3,p0,p1] vs gt
                    float l2 = smooth_l1(a2, b0) + smooth_l1(a3, b1) +
                               smooth_l1(a0, b2) + smooth_l1(a1, b3);
                    acc[base[k] + 0] += fminf(l1, l2) * m;
                    acc[base[k] + 1] += m;
                }
            }
        }

        // ---- len/angle: sol=ch5/6 (acc 16..18), tp=ch12/13 (19..21) ----
        {
            const int cl[2]   = {5, 12};
            const int base[2] = {16, 19};
#pragma unroll
            for (int k = 0; k < 2; ++k) {
                float4 pl = pb[(size_t)(cl[k] + 0) * HW4];
                float4 pa = pb[(size_t)(cl[k] + 1) * HW4];
                float4 gl = gb[(size_t)(cl[k] + 0) * HW4];
                float4 ga = gb[(size_t)(cl[k] + 1) * HW4];
#pragma unroll
                for (int j = 0; j < 4; ++j) {
                    float glv = get4(gl, j);
                    float m = (glv != 0.0f) ? 1.0f : 0.0f;
                    acc[base[k] + 0] += smooth_l1(sigmoid_fast(get4(pl, j)), glv) * m;
                    acc[base[k] + 1] += smooth_l1(sigmoid_fast(get4(pa, j)), get4(ga, j)) * m;
                    acc[base[k] + 2] += m;
                }
            }
        }
    }

    // ---- wave (64-lane) butterfly reduce each accumulator ----
#pragma unroll
    for (int i = 0; i < NACC; ++i) {
        float v = acc[i];
#pragma unroll
        for (int off = 32; off > 0; off >>= 1) v += __shfl_down(v, off, 64);
        acc[i] = v;
    }

    __shared__ float red[4][NACC];
    const int lane = threadIdx.x & 63;
    const int wid  = threadIdx.x >> 6;
    if (lane == 0) {
#pragma unroll
        for (int i = 0; i < NACC; ++i) red[wid][i] = acc[i];
    }
    __syncthreads();
    if (threadIdx.x < NACC) {
        float s = red[0][threadIdx.x] + red[1][threadIdx.x] +
                  red[2][threadIdx.x] + red[3][threadIdx.x];
        atomicAdd(&ws[threadIdx.x], (double)s);
    }
}

__global__ void finalize_kernel(const double* __restrict__ ws, float* __restrict__ out) {
    if (threadIdx.x == 0 && blockIdx.x == 0) {
        const double N = (double)NPIX;
        double line_seg   = ws[0] / ws[2]  +  1.0 * (ws[1]  / (N - ws[2]));
        double junc_seg   = ws[3] / ws[5]  + 30.0 * (ws[4]  / (N - ws[5]));
        double sol_center = ws[6] / ws[8]  + 30.0 * (ws[7]  / (N - ws[8]));
        double tp_center  = ws[9] / ws[11] + 30.0 * (ws[10] / (N - ws[11]));
        double sol_disp   = ws[12] / ws[13];
        double tp_disp    = ws[14] / ws[15];
        double sol_len    = ws[16] / ws[18];
        double sol_angle  = ws[17] / ws[18];
        double tp_len     = ws[19] / ws[21];
        double tp_angle   = ws[20] / ws[21];
        double total = 10.0 * tp_center + tp_disp + tp_len + tp_angle +
                       sol_center + sol_disp + sol_len + sol_angle +
                       line_seg + junc_seg;
        out[0] = (float)total;
    }
}

extern "C" void kernel_launch(void* const* d_in, const int* in_sizes, int n_in,
                              void* d_out, int out_size, void* d_ws, size_t ws_size,
                              hipStream_t stream) {
    const float* preds = (const float*)d_in[0];
    const float* gts   = (const float*)d_in[1];
    double* ws = (double*)d_ws;

    // d_ws is re-poisoned to 0xAA before every launch — zero the accumulators.
    hipMemsetAsync(d_ws, 0, NACC * sizeof(double), stream);

    loss_kernel<<<GRID_BLOCKS, 256, 0, stream>>>(preds, gts, ws);
    finalize_kernel<<<1, 64, 0, stream>>>(ws, (float*)d_out);
}

// Round 4
// 291.626 us; speedup vs baseline: 1.0197x; 1.0044x over previous
//
#include <hip/hip_runtime.h>
#include <math.h>

// Problem geometry (fixed by the reference): B=32, C=16, H=W=256.
#define HW 65536
#define HW4 16384          // float4 groups per channel-plane
#define CTOT 16
#define BATCH 32
#define NPIX (BATCH * HW)  // 2,097,152 pixels per channel
#define NGRP (NPIX / 4)    // 524,288 float4 groups per channel

// Accumulator slots in workspace (double[22]):
//  0.. 2 : ch15 line_seg  (sumPosLoss, sumNegLoss, cntPos)
//  3.. 5 : ch14 junc_seg
//  6.. 8 : ch0  sol_center
//  9..11 : ch7  tp_center
// 12..13 : sol disp (sumMinLoss, cntPos)
// 14..15 : tp  disp
// 16..18 : sol len/angle (sumLen, sumAngle, cntPos)
// 19..21 : tp  len/angle
#define NACC 22

// 2048 blocks, task-specialized, each block sweeps a CONTIGUOUS span of its
// task's (b,hw4) group space front-to-back (dense streams, not 1-KB islands):
//   blocks    0..511  : 4 BCE tasks x 128 blocks, span 4096 groups, 2 streams
//   blocks  512..1535 : 2 disp tasks x 512 blocks, span 1024 groups, 8 streams
//   blocks 1536..2047 : 2 len/angle  x 256 blocks, span 2048 groups, 4 streams
// Every thread performs exactly 32 float4 loads (balanced).
#define GRID_BLOCKS 2048

__device__ __forceinline__ float smooth_l1(float p, float g) {
    float d = fabsf(p - g);
    return (d < 1.0f) ? 0.5f * d * d : d - 0.5f;
}
// a=|x| >= 0 so 1+exp(-a) in (1,2]: plain __logf is safe (abs err < 6e-8).
__device__ __forceinline__ float bce_logits(float x, float t) {
    float e = __expf(-fabsf(x));
    return fmaxf(x, 0.0f) - x * t + __logf(1.0f + e);
}
__device__ __forceinline__ float sigmoid_fast(float x) {
    return __builtin_amdgcn_rcpf(1.0f + __expf(-x));
}
__device__ __forceinline__ float get4(const float4& v, int j) {
    return j == 0 ? v.x : (j == 1 ? v.y : (j == 2 ? v.z : v.w));
}

__global__ __launch_bounds__(256) void loss_kernel(const float* __restrict__ preds,
                                                   const float* __restrict__ gts,
                                                   double* __restrict__ ws) {
    const float4* pf = (const float4*)preds;
    const float4* gf = (const float4*)gts;
    const int blk = blockIdx.x;
    const int tid = threadIdx.x;

    float acc0 = 0.0f, acc1 = 0.0f, acc2 = 0.0f;
    int base, nacc;

    if (blk < 512) {
        // ---------------- BCE task: 2 dense streams ----------------
        const int task = blk >> 7;                    // 0..3
        const int chs[4]   = {15, 14, 0, 7};
        const int bases[4] = {0, 3, 6, 9};
        const int ch = chs[task];
        base = bases[task];
        nacc = 3;
        const int lblk = blk & 127;
        // contiguous span of 4096 groups; b uniform within span
        const int start = lblk << 12;                 // lblk * 4096
        const int b = start >> 14;
        const int hw4s = start & (HW4 - 1);
        const size_t off = ((size_t)b * CTOT + ch) * HW4 + hw4s;
        const float4* pp = pf + off;
        const float4* gp = gf + off;
#pragma unroll 4
        for (int i = 0; i < 16; ++i) {
            const int o = (i << 8) + tid;             // sweep 4 KB windows forward
            float4 p = pp[o];
            float4 t = gp[o];
#pragma unroll
            for (int j = 0; j < 4; ++j) {
                float x  = get4(p, j);
                float tv = get4(t, j);
                float loss = bce_logits(x, tv);
                float pos  = (tv != 0.0f) ? 1.0f : 0.0f;
                acc0 += loss * pos;
                acc1 += loss * (1.0f - pos);
                acc2 += pos;
            }
        }
    } else if (blk < 1536) {
        // ---------------- displacement task: 8 dense streams ----------------
        const int task = (blk - 512) >> 9;            // 0..1
        const int c0 = task == 0 ? 1 : 8;
        base = task == 0 ? 12 : 14;
        nacc = 2;
        const int lblk = (blk - 512) & 511;
        const int start = lblk << 10;                 // span 1024 groups
        const int b = start >> 14;
        const int hw4s = start & (HW4 - 1);
        const size_t off = ((size_t)b * CTOT + c0) * HW4 + hw4s;
        const float4* pp = pf + off;
        const float4* gp = gf + off;
#pragma unroll 2
        for (int i = 0; i < 4; ++i) {
            const int o = (i << 8) + tid;
            float4 p0 = pp[o + 0 * HW4];
            float4 p1 = pp[o + 1 * HW4];
            float4 p2 = pp[o + 2 * HW4];
            float4 p3 = pp[o + 3 * HW4];
            float4 g0 = gp[o + 0 * HW4];
            float4 g1 = gp[o + 1 * HW4];
            float4 g2 = gp[o + 2 * HW4];
            float4 g3 = gp[o + 3 * HW4];
#pragma unroll
            for (int j = 0; j < 4; ++j) {
                float a0 = get4(p0, j), a1 = get4(p1, j), a2 = get4(p2, j), a3 = get4(p3, j);
                float b0 = get4(g0, j), b1 = get4(g1, j), b2 = get4(g2, j), b3 = get4(g3, j);
                float posv = fabsf(b0) + fabsf(b1) + fabsf(b2) + fabsf(b3);
                float m = (posv != 0.0f) ? 1.0f : 0.0f;
                float l1 = smooth_l1(a0, b0) + smooth_l1(a1, b1) +
                           smooth_l1(a2, b2) + smooth_l1(a3, b3);
                // swap = concat(pred[2:], pred[:2]) -> [p2,p3,p0,p1] vs gt
                float l2 = smooth_l1(a2, b0) + smooth_l1(a3, b1) +
                           smooth_l1(a0, b2) + smooth_l1(a1, b3);
                acc0 += fminf(l1, l2) * m;
                acc1 += m;
            }
        }
    } else {
        // ---------------- len/angle task: 4 dense streams ----------------
        const int task = (blk - 1536) >> 8;           // 0..1
        const int cl = task == 0 ? 5 : 12;
        base = task == 0 ? 16 : 19;
        nacc = 3;
        const int lblk = (blk - 1536) & 255;
        const int start = lblk << 11;                 // span 2048 groups
        const int b = start >> 14;
        const int hw4s = start & (HW4 - 1);
        const size_t off = ((size_t)b * CTOT + cl) * HW4 + hw4s;
        const float4* pp = pf + off;
        const float4* gp = gf + off;
#pragma unroll 2
        for (int i = 0; i < 8; ++i) {
            const int o = (i << 8) + tid;
            float4 pl = pp[o + 0 * HW4];
            float4 pa = pp[o + 1 * HW4];
            float4 gl = gp[o + 0 * HW4];
            float4 ga = gp[o + 1 * HW4];
#pragma unroll
            for (int j = 0; j < 4; ++j) {
                float glv = get4(gl, j);
                float m = (glv != 0.0f) ? 1.0f : 0.0f;
                acc0 += smooth_l1(sigmoid_fast(get4(pl, j)), glv) * m;
                acc1 += smooth_l1(sigmoid_fast(get4(pa, j)), get4(ga, j)) * m;
                acc2 += m;
            }
        }
    }

    // ---- wave (64-lane) butterfly reduce the (up to) 3 accumulators ----
#pragma unroll
    for (int off = 32; off > 0; off >>= 1) {
        acc0 += __shfl_down(acc0, off, 64);
        acc1 += __shfl_down(acc1, off, 64);
        acc2 += __shfl_down(acc2, off, 64);
    }

    __shared__ float red[4][3];
    const int lane = threadIdx.x & 63;
    const int wid  = threadIdx.x >> 6;
    if (lane == 0) { red[wid][0] = acc0; red[wid][1] = acc1; red[wid][2] = acc2; }
    __syncthreads();
    if (threadIdx.x == 0) {
        float s0 = red[0][0] + red[1][0] + red[2][0] + red[3][0];
        float s1 = red[0][1] + red[1][1] + red[2][1] + red[3][1];
        float s2 = red[0][2] + red[1][2] + red[2][2] + red[3][2];
        atomicAdd(&ws[base + 0], (double)s0);
        atomicAdd(&ws[base + 1], (double)s1);
        if (nacc == 3) atomicAdd(&ws[base + 2], (double)s2);
    }
}

__global__ void finalize_kernel(const double* __restrict__ ws, float* __restrict__ out) {
    if (threadIdx.x == 0 && blockIdx.x == 0) {
        const double N = (double)NPIX;
        double line_seg   = ws[0] / ws[2]  +  1.0 * (ws[1]  / (N - ws[2]));
        double junc_seg   = ws[3] / ws[5]  + 30.0 * (ws[4]  / (N - ws[5]));
        double sol_center = ws[6] / ws[8]  + 30.0 * (ws[7]  / (N - ws[8]));
        double tp_center  = ws[9] / ws[11] + 30.0 * (ws[10] / (N - ws[11]));
        double sol_disp   = ws[12] / ws[13];
        double tp_disp    = ws[14] / ws[15];
        double sol_len    = ws[16] / ws[18];
        double sol_angle  = ws[17] / ws[18];
        double tp_len     = ws[19] / ws[21];
        double tp_angle   = ws[20] / ws[21];
        double total = 10.0 * tp_center + tp_disp + tp_len + tp_angle +
                       sol_center + sol_disp + sol_len + sol_angle +
                       line_seg + junc_seg;
        out[0] = (float)total;
    }
}

extern "C" void kernel_launch(void* const* d_in, const int* in_sizes, int n_in,
                              void* d_out, int out_size, void* d_ws, size_t ws_size,
                              hipStream_t stream) {
    const float* preds = (const float*)d_in[0];
    const float* gts   = (const float*)d_in[1];
    double* ws = (double*)d_ws;

    // d_ws is re-poisoned to 0xAA before every launch — zero the accumulators.
    hipMemsetAsync(d_ws, 0, NACC * sizeof(double), stream);

    loss_kernel<<<GRID_BLOCKS, 256, 0, stream>>>(preds, gts, ws);
    finalize_kernel<<<1, 64, 0, stream>>>(ws, (float*)d_out);
}

// Round 5
// 282.921 us; speedup vs baseline: 1.0511x; 1.0308x over previous
//
#include <hip/hip_runtime.h>
#include <math.h>

// Problem geometry (fixed by the reference): B=32, C=16, H=W=256.
#define HW 65536
#define HW4 16384          // float4 groups per channel-plane
#define CTOT 16
#define BATCH 32
#define NPIX (BATCH * HW)  // 2,097,152 pixels per channel
#define NGRP (NPIX / 4)    // 524,288 float4 groups per channel

// Accumulator slots in workspace (double[22]):
//  0.. 2 : ch15 line_seg  (sumPosLoss, sumNegLoss, cntPos)
//  3.. 5 : ch14 junc_seg
//  6.. 8 : ch0  sol_center
//  9..11 : ch7  tp_center
// 12..13 : sol disp (sumMinLoss, cntPos)
// 14..15 : tp  disp
// 16..18 : sol len/angle (sumLen, sumAngle, cntPos)
// 19..21 : tp  len/angle
#define NACC 22

// 2048 blocks x 256 threads = 524,288 threads = NGRP -> exactly 1 group/thread.
// b = blockIdx>>6 is wave-uniform; hw4 = (blockIdx&63)*256 + tid.
#define GRID_BLOCKS 2048

__device__ __forceinline__ float smooth_l1(float p, float g) {
    float d = fabsf(p - g);
    return (d < 1.0f) ? 0.5f * d * d : d - 0.5f;
}
// a=|x| >= 0 so 1+exp(-a) in (1,2]: plain __logf is safe (abs err < 6e-8).
__device__ __forceinline__ float bce_logits(float x, float t) {
    float e = __expf(-fabsf(x));
    return fmaxf(x, 0.0f) - x * t + __logf(1.0f + e);
}
__device__ __forceinline__ float sigmoid_fast(float x) {
    return __builtin_amdgcn_rcpf(1.0f + __expf(-x));
}
__device__ __forceinline__ float get4(const float4& v, int j) {
    return j == 0 ? v.x : (j == 1 ? v.y : (j == 2 ? v.z : v.w));
}

// launch_bounds(256, 2): allow up to 256 VGPR/wave so all 32 dwordx4 loads
// (128 VGPRs of data) can be live simultaneously -> 32 KB in flight per wave.
__global__ __launch_bounds__(256, 2) void loss_kernel(const float* __restrict__ preds,
                                                      const float* __restrict__ gts,
                                                      double* __restrict__ ws) {
    const float4* pf = (const float4*)preds;
    const float4* gf = (const float4*)gts;

    // Wave-uniform batch index, per-thread spatial index.
    const int b   = blockIdx.x >> 6;                       // 0..31, uniform
    const int hw4 = ((blockIdx.x & 63) << 8) + threadIdx.x; // 0..16383
    const float4* pb = pf + (size_t)b * (CTOT * HW4) + hw4;
    const float4* gb = gf + (size_t)b * (CTOT * HW4) + hw4;

    // ---- Phase 1: issue ALL 32 independent loads before any compute ----
    float4 P[CTOT], G[CTOT];
#pragma unroll
    for (int ch = 0; ch < CTOT; ++ch) {
        P[ch] = pb[(size_t)ch * HW4];
        G[ch] = gb[(size_t)ch * HW4];
    }

    // ---- Phase 2: compute all sub-losses ----
    float acc[NACC];
#pragma unroll
    for (int i = 0; i < NACC; ++i) acc[i] = 0.0f;

    // 4 weighted-BCE channels
    {
        const int chs[4]   = {15, 14, 0, 7};
        const int bases[4] = {0, 3, 6, 9};
#pragma unroll
        for (int k = 0; k < 4; ++k) {
            const float4& p = P[chs[k]];
            const float4& t = G[chs[k]];
            const int bs = bases[k];
#pragma unroll
            for (int j = 0; j < 4; ++j) {
                float x  = get4(p, j);
                float tv = get4(t, j);
                float loss = bce_logits(x, tv);
                float pos  = (tv != 0.0f) ? 1.0f : 0.0f;
                acc[bs + 0] += loss * pos;
                acc[bs + 1] += loss * (1.0f - pos);
                acc[bs + 2] += pos;
            }
        }
    }

    // displacement groups: sol=ch1..4 (acc 12,13), tp=ch8..11 (14,15)
    {
        const int c0s[2]   = {1, 8};
        const int bases[2] = {12, 14};
#pragma unroll
        for (int k = 0; k < 2; ++k) {
            const int c0 = c0s[k];
            const int bs = bases[k];
#pragma unroll
            for (int j = 0; j < 4; ++j) {
                float a0 = get4(P[c0 + 0], j), a1 = get4(P[c0 + 1], j);
                float a2 = get4(P[c0 + 2], j), a3 = get4(P[c0 + 3], j);
                float b0 = get4(G[c0 + 0], j), b1 = get4(G[c0 + 1], j);
                float b2 = get4(G[c0 + 2], j), b3 = get4(G[c0 + 3], j);
                float posv = fabsf(b0) + fabsf(b1) + fabsf(b2) + fabsf(b3);
                float m = (posv != 0.0f) ? 1.0f : 0.0f;
                float l1 = smooth_l1(a0, b0) + smooth_l1(a1, b1) +
                           smooth_l1(a2, b2) + smooth_l1(a3, b3);
                // swap = concat(pred[2:], pred[:2]) -> [p2,p3,p0,p1] vs gt
                float l2 = smooth_l1(a2, b0) + smooth_l1(a3, b1) +
                           smooth_l1(a0, b2) + smooth_l1(a1, b3);
                acc[bs + 0] += fminf(l1, l2) * m;
                acc[bs + 1] += m;
            }
        }
    }

    // len/angle: sol=ch5/6 (acc 16..18), tp=ch12/13 (19..21)
    {
        const int cls[2]   = {5, 12};
        const int bases[2] = {16, 19};
#pragma unroll
        for (int k = 0; k < 2; ++k) {
            const int cl = cls[k];
            const int bs = bases[k];
#pragma unroll
            for (int j = 0; j < 4; ++j) {
                float glv = get4(G[cl], j);
                float m = (glv != 0.0f) ? 1.0f : 0.0f;
                acc[bs + 0] += smooth_l1(sigmoid_fast(get4(P[cl], j)), glv) * m;
                acc[bs + 1] += smooth_l1(sigmoid_fast(get4(P[cl + 1], j)), get4(G[cl + 1], j)) * m;
                acc[bs + 2] += m;
            }
        }
    }

    // ---- wave (64-lane) butterfly reduce each accumulator ----
#pragma unroll
    for (int i = 0; i < NACC; ++i) {
        float v = acc[i];
#pragma unroll
        for (int off = 32; off > 0; off >>= 1) v += __shfl_down(v, off, 64);
        acc[i] = v;
    }

    __shared__ float red[4][NACC];
    const int lane = threadIdx.x & 63;
    const int wid  = threadIdx.x >> 6;
    if (lane == 0) {
#pragma unroll
        for (int i = 0; i < NACC; ++i) red[wid][i] = acc[i];
    }
    __syncthreads();
    if (threadIdx.x < NACC) {
        float s = red[0][threadIdx.x] + red[1][threadIdx.x] +
                  red[2][threadIdx.x] + red[3][threadIdx.x];
        atomicAdd(&ws[threadIdx.x], (double)s);
    }
}

__global__ void finalize_kernel(const double* __restrict__ ws, float* __restrict__ out) {
    if (threadIdx.x == 0 && blockIdx.x == 0) {
        const double N = (double)NPIX;
        double line_seg   = ws[0] / ws[2]  +  1.0 * (ws[1]  / (N - ws[2]));
        double junc_seg   = ws[3] / ws[5]  + 30.0 * (ws[4]  / (N - ws[5]));
        double sol_center = ws[6] / ws[8]  + 30.0 * (ws[7]  / (N - ws[8]));
        double tp_center  = ws[9] / ws[11] + 30.0 * (ws[10] / (N - ws[11]));
        double sol_disp   = ws[12] / ws[13];
        double tp_disp    = ws[14] / ws[15];
        double sol_len    = ws[16] / ws[18];
        double sol_angle  = ws[17] / ws[18];
        double tp_len     = ws[19] / ws[21];
        double tp_angle   = ws[20] / ws[21];
        double total = 10.0 * tp_center + tp_disp + tp_len + tp_angle +
                       sol_center + sol_disp + sol_len + sol_angle +
                       line_seg + junc_seg;
        out[0] = (float)total;
    }
}

extern "C" void kernel_launch(void* const* d_in, const int* in_sizes, int n_in,
                              void* d_out, int out_size, void* d_ws, size_t ws_size,
                              hipStream_t stream) {
    const float* preds = (const float*)d_in[0];
    const float* gts   = (const float*)d_in[1];
    double* ws = (double*)d_ws;

    // d_ws is re-poisoned to 0xAA before every launch — zero the accumulators.
    hipMemsetAsync(d_ws, 0, NACC * sizeof(double), stream);

    loss_kernel<<<GRID_BLOCKS, 256, 0, stream>>>(preds, gts, ws);
    finalize_kernel<<<1, 64, 0, stream>>>(ws, (float*)d_out);
}